// Round 1
// 1276.925 us; speedup vs baseline: 1.3456x; 1.3456x over previous
//
#include <hip/hip_runtime.h>
#include <cstdint>
#include <cstddef>

// Problem constants (GraphProcessor): N=50000 nodes, E=800000 edges, D=128, 4 blocks.
// KEY: reference's scan body ignores the carry -> only block index 3's params matter.
#define D 128
#define NEDGE 800000
#define NNODE 50000

typedef __attribute__((ext_vector_type(8))) short short8;   // 8 x bf16 (4 VGPRs)
typedef __attribute__((ext_vector_type(4))) float f32x4;    // MFMA accumulator

// ---- helpers ---------------------------------------------------------------
__device__ __forceinline__ unsigned short f2bf(float f) {
  // round-half-away bf16 truncation (error <= 0.5 ulp, plenty under 0.16 absmax)
  return (unsigned short)((__float_as_uint(f) + 0x8000u) >> 16);
}
__device__ __forceinline__ unsigned pack2(float lo, float hi) {
  // two floats -> two bf16 packed in one u32 via v_perm (bytes 2,3 of each)
  return __builtin_amdgcn_perm(__float_as_uint(hi) + 0x8000u,
                               __float_as_uint(lo) + 0x8000u, 0x07060302u);
}
__device__ __forceinline__ void gl_lds16(const void* g, void* l) {
  // async global->LDS, width 16B; LDS dest = wave-uniform base + lane*16
  __builtin_amdgcn_global_load_lds(
      (const __attribute__((address_space(1))) unsigned*)g,
      (__attribute__((address_space(3))) unsigned*)l, 16, 0, 0);
}

// ---- weight prep: block-3 slice -> bf16, transposed, chunked, padded -------
// Image layout per matrix: chunks c of 32 k; within chunk: 128 rows (n) x 40 bf16
// (32 real k + 8 pad). This is byte-identical to the LDS B-chunk layout, so
// staging is a verbatim global_load_lds copy. Pads are never read by B-frags.
// ushort offsets inside img: W1E 0 (12 ch), W2E 61440, W3E 81920,
//                            W1N 102400 (8 ch), W2N 143360, W3N 163840.
__global__ void prep_weights(const float* __restrict__ ew1, const float* __restrict__ ew2,
                             const float* __restrict__ ew3, const float* __restrict__ nw1,
                             const float* __restrict__ nw2, const float* __restrict__ nw3,
                             unsigned short* __restrict__ img) {
  int t = blockIdx.x * 256 + threadIdx.x;       // 36 chunks * 128 * 32 = 147456
  int kk = t & 31;
  int n  = (t >> 5) & 127;
  int c  = t >> 12;
  if (c >= 36) return;
  const float* src; int cl; int ioff;
  if      (c < 12) { src = ew1; cl = c;      ioff = 0;      }
  else if (c < 16) { src = ew2; cl = c - 12; ioff = 61440;  }
  else if (c < 20) { src = ew3; cl = c - 16; ioff = 81920;  }
  else if (c < 28) { src = nw1; cl = c - 20; ioff = 102400; }
  else if (c < 32) { src = nw2; cl = c - 28; ioff = 143360; }
  else             { src = nw3; cl = c - 32; ioff = 163840; }
  // src is (K,128) row-major; element [cl*32+kk][n]
  img[ioff + (cl * 128 + n) * 40 + kk] = f2bf(src[(cl * 32 + kk) * 128 + n]);
}

// ---- fused 3-layer MLP + LayerNorm (+ scatter-add for edges) ---------------
// Block tile: 128 rows x 128 cols. 4 waves in 2x2; wave tile 64x64 = 4x4 frags
// of mfma_f32_16x16x32_bf16. Layer 1: K = NCH*32 (double-buffered A & B LDS
// chunks). Layers 2/3: K=128, whole W staged in LDS, barrier-free k-loop.
//
// OCCUPANCY: h1 and h2 SHARE one 34816 B LDS buffer (h2 is only written after
// all layer-2 reads of h1 completed, enforced by a barrier). Total LDS is
// 77824 B -> 2 workgroups/CU (was 112640 B -> 1 wg/CU, 1 wave/SIMD, no
// latency hiding; all pipes <17% busy).
template <int NCH, bool EDGE>
__global__ __launch_bounds__(256, 2)
void mlp_fused(const float* __restrict__ srcA,   // x
               const float* __restrict__ srcB,   // edge: edge_attr ; node: agg
               const int* __restrict__ rowidx, const int* __restrict__ colidx,
               const unsigned short* __restrict__ w1,
               const unsigned short* __restrict__ w2,
               const unsigned short* __restrict__ w3,
               const float* __restrict__ b1, const float* __restrict__ b2,
               const float* __restrict__ b3,
               const float* __restrict__ gam, const float* __restrict__ bet,
               float* __restrict__ outp, float* __restrict__ agg, int M) {
  // LDS: [stage 4x10240][h 128x136 bf16 (h1 then h2 in place)][stats 128x2x2 f32]
  __shared__ __align__(16) char lds[77824];
  char*  sStage = lds;                     // 40960
  char*  sH     = lds + 40960;             // 34816 (h1, later h2)
  float* sStats = (float*)(lds + 75776);   // 2048

  const int tid  = threadIdx.x;
  const int wave = tid >> 6, lane = tid & 63;
  const int wm = wave >> 1, wn = wave & 1;
  const int lr = lane & 15, lq = lane >> 4;
  const int m0 = blockIdx.x * 128;

  // ---- staging thread mapping: 2 threads per row, 16 floats each ----
  const int sr = tid >> 1;     // tile row 0..127
  const int ssub = tid & 1;    // which 16-float half of the 32-float chunk
  const float* pA0; const float* pA1; const float* pA2 = nullptr;
  bool svalid = true;
  if (EDGE) {
    int e = m0 + sr;
    pA0 = srcA + (size_t)rowidx[e] * D;   // x[row]
    pA1 = srcA + (size_t)colidx[e] * D;   // x[col]
    pA2 = srcB + (size_t)e * D;           // edge_attr[e]
  } else {
    int node = m0 + sr;
    svalid = node < M;
    pA0 = srcA + (size_t)node * D;        // x[node]
    pA1 = srcB + (size_t)node * D;        // agg[node]
  }

  float4 av[4];
  auto loadA = [&](int kc) {
    const float* base;
    if (EDGE) base = (kc < 4) ? pA0 + kc * 32
                   : (kc < 8) ? pA1 + (kc - 4) * 32
                              : pA2 + (kc - 8) * 32;
    else      base = (kc < 4) ? pA0 + kc * 32 : pA1 + (kc - 4) * 32;
    if (!EDGE && !svalid) {
#pragma unroll
      for (int i = 0; i < 4; i++) av[i] = make_float4(0.f, 0.f, 0.f, 0.f);
    } else {
#pragma unroll
      for (int i = 0; i < 4; i++) av[i] = *(const float4*)(base + ssub * 16 + i * 4);
    }
  };
  auto storeA = [&](int bb) {
    char* dst = sStage + bb * 10240 + (sr * 40 + ssub * 16) * 2;
#pragma unroll
    for (int i = 0; i < 4; i++) {
      uint2 pk;
      pk.x = pack2(av[i].x, av[i].y);
      pk.y = pack2(av[i].z, av[i].w);
      *(uint2*)(dst + i * 8) = pk;
    }
  };
  auto stageB = [&](int bb, int kc) {
    const char* g = (const char*)w1 + kc * 10240;
    char* l = sStage + 20480 + bb * 10240;
    for (int s = wave; s < 10; s += 4) gl_lds16(g + s * 1024 + lane * 16, l + s * 1024);
  };
  auto stageFull = [&](const unsigned short* w) {  // 40960 B = W2 or W3 image
    for (int s = wave; s < 40; s += 4)
      gl_lds16((const char*)w + s * 1024 + lane * 16, sStage + s * 1024);
  };

  const f32x4 fz = {0.f, 0.f, 0.f, 0.f};
  f32x4 acc[4][4];
#pragma unroll
  for (int mt = 0; mt < 4; mt++)
#pragma unroll
    for (int nt = 0; nt < 4; nt++) acc[mt][nt] = fz;

  // ================= layer 1: [128 x NCH*32] @ [NCH*32 x 128] ===============
  loadA(0); storeA(0); stageB(0, 0);
  __syncthreads();
  for (int kc = 0; kc < NCH; kc++) {
    int cur = kc & 1;
    if (kc + 1 < NCH) { stageB(cur ^ 1, kc + 1); loadA(kc + 1); }
    {
      const char* pa = sStage + cur * 10240;
      const char* pb = sStage + 20480 + cur * 10240;
      short8 a[4], b[4];
#pragma unroll
      for (int t2 = 0; t2 < 4; t2++) {
        a[t2] = *(const short8*)(pa + (wm * 64 + t2 * 16 + lr) * 80 + lq * 16);
        b[t2] = *(const short8*)(pb + (wn * 64 + t2 * 16 + lr) * 80 + lq * 16);
      }
#pragma unroll
      for (int mt = 0; mt < 4; mt++)
#pragma unroll
        for (int nt = 0; nt < 4; nt++)
          acc[mt][nt] = __builtin_amdgcn_mfma_f32_16x16x32_bf16(a[mt], b[nt], acc[mt][nt], 0, 0, 0);
    }
    if (kc + 1 < NCH) storeA(cur ^ 1);
    __syncthreads();
  }

  // h1 = relu(acc + b1) -> LDS bf16 (row stride 136: 2-way-only bank aliasing)
  {
    float bb[4];
#pragma unroll
    for (int nt = 0; nt < 4; nt++) bb[nt] = b1[wn * 64 + nt * 16 + lr];
#pragma unroll
    for (int mt = 0; mt < 4; mt++) {
      int row = wm * 64 + mt * 16 + lq * 4;
#pragma unroll
      for (int nt = 0; nt < 4; nt++) {
        int col = wn * 64 + nt * 16 + lr;
#pragma unroll
        for (int r = 0; r < 4; r++) {
          float v = fmaxf(acc[mt][nt][r] + bb[nt], 0.f);
          *(unsigned short*)(sH + ((row + r) * 136 + col) * 2) = f2bf(v);
        }
      }
    }
  }
  stageFull(w2);        // stage region is free: last layer-1 barrier passed
  __syncthreads();      // h1 + W2 visible

  // ================= layer 2: [128x128] @ [128x128] =========================
#pragma unroll
  for (int mt = 0; mt < 4; mt++)
#pragma unroll
    for (int nt = 0; nt < 4; nt++) acc[mt][nt] = fz;
#pragma unroll
  for (int kc = 0; kc < 4; kc++) {
    short8 a[4], b[4];
#pragma unroll
    for (int t2 = 0; t2 < 4; t2++) {
      a[t2] = *(const short8*)(sH + (wm * 64 + t2 * 16 + lr) * 272 + kc * 64 + lq * 16);
      b[t2] = *(const short8*)(sStage + kc * 10240 + (wn * 64 + t2 * 16 + lr) * 80 + lq * 16);
    }
#pragma unroll
    for (int mt = 0; mt < 4; mt++)
#pragma unroll
      for (int nt = 0; nt < 4; nt++)
        acc[mt][nt] = __builtin_amdgcn_mfma_f32_16x16x32_bf16(a[mt], b[nt], acc[mt][nt], 0, 0, 0);
  }
  __syncthreads();      // ALL waves' h1 (A) and W2 (B) LDS reads drained
  // h2 = relu(acc + b2) -> written IN PLACE over h1 (reads are done)
  {
    float bb[4];
#pragma unroll
    for (int nt = 0; nt < 4; nt++) bb[nt] = b2[wn * 64 + nt * 16 + lr];
#pragma unroll
    for (int mt = 0; mt < 4; mt++) {
      int row = wm * 64 + mt * 16 + lq * 4;
#pragma unroll
      for (int nt = 0; nt < 4; nt++) {
        int col = wn * 64 + nt * 16 + lr;
#pragma unroll
        for (int r = 0; r < 4; r++) {
          float v = fmaxf(acc[mt][nt][r] + bb[nt], 0.f);
          *(unsigned short*)(sH + ((row + r) * 136 + col) * 2) = f2bf(v);
        }
      }
    }
  }
  stageFull(w3);        // W2 reads done at the barrier above -> safe overwrite
  __syncthreads();      // h2 + W3 visible

  // ================= layer 3: [128x128] @ [128x128] =========================
#pragma unroll
  for (int mt = 0; mt < 4; mt++)
#pragma unroll
    for (int nt = 0; nt < 4; nt++) acc[mt][nt] = fz;
#pragma unroll
  for (int kc = 0; kc < 4; kc++) {
    short8 a[4], b[4];
#pragma unroll
    for (int t2 = 0; t2 < 4; t2++) {
      a[t2] = *(const short8*)(sH + (wm * 64 + t2 * 16 + lr) * 272 + kc * 64 + lq * 16);
      b[t2] = *(const short8*)(sStage + kc * 10240 + (wn * 64 + t2 * 16 + lr) * 80 + lq * 16);
    }
#pragma unroll
    for (int mt = 0; mt < 4; mt++)
#pragma unroll
      for (int nt = 0; nt < 4; nt++)
        acc[mt][nt] = __builtin_amdgcn_mfma_f32_16x16x32_bf16(a[mt], b[nt], acc[mt][nt], 0, 0, 0);
  }

  // ================= epilogue: bias + LayerNorm + residual (+scatter) ======
  float b3v[4], gv[4], bev[4]; int colv[4];
#pragma unroll
  for (int nt = 0; nt < 4; nt++) {
    int col = wn * 64 + nt * 16 + lr;
    colv[nt] = col;
    b3v[nt] = b3[col]; gv[nt] = gam[col]; bev[nt] = bet[col];
  }
  // row stats: sum over this wave's 64 cols via in-quad shuffle reduction
#pragma unroll
  for (int mt = 0; mt < 4; mt++) {
#pragma unroll
    for (int r = 0; r < 4; r++) {
      float s = 0.f, ss = 0.f;
#pragma unroll
      for (int nt = 0; nt < 4; nt++) {
        float v = acc[mt][nt][r] + b3v[nt];
        acc[mt][nt][r] = v;
        s += v; ss += v * v;
      }
#pragma unroll
      for (int o = 1; o < 16; o <<= 1) { s += __shfl_xor(s, o); ss += __shfl_xor(ss, o); }
      if (lr == 0) {
        int row = wm * 64 + mt * 16 + lq * 4 + r;
        sStats[(row * 2 + wn) * 2 + 0] = s;
        sStats[(row * 2 + wn) * 2 + 1] = ss;
      }
    }
  }
  __syncthreads();
#pragma unroll
  for (int mt = 0; mt < 4; mt++) {
#pragma unroll
    for (int r = 0; r < 4; r++) {
      int row = wm * 64 + mt * 16 + lq * 4 + r;
      int gm = m0 + row;
      float s  = sStats[(row * 2 + 0) * 2 + 0] + sStats[(row * 2 + 1) * 2 + 0];
      float ss = sStats[(row * 2 + 0) * 2 + 1] + sStats[(row * 2 + 1) * 2 + 1];
      float mean = s * (1.f / 128.f);
      float var  = ss * (1.f / 128.f) - mean * mean;
      float rstd = rsqrtf(var + 1e-5f);
      if (EDGE) {
        int cv = colidx[gm];
        float* aggrow = agg + (size_t)cv * D;
        const float* res = srcB + (size_t)gm * D;   // edge_attr residual
        float* orow = outp + (size_t)gm * D;
#pragma unroll
        for (int nt = 0; nt < 4; nt++) {
          int col = colv[nt];
          float e = (acc[mt][nt][r] - mean) * rstd * gv[nt] + bev[nt];
          atomicAdd(aggrow + col, e);               // segment_sum(e, col)
          orow[col] = e + res[col];                 // out_e = e + edge_attr
        }
      } else if (gm < M) {
        const float* res = srcA + (size_t)gm * D;   // x residual
        float* orow = outp + (size_t)gm * D;
#pragma unroll
        for (int nt = 0; nt < 4; nt++) {
          int col = colv[nt];
          float e = (acc[mt][nt][r] - mean) * rstd * gv[nt] + bev[nt];
          orow[col] = e + res[col];                 // out_x = nx + x
        }
      }
    }
  }
}

// ---- launch ----------------------------------------------------------------
extern "C" void kernel_launch(void* const* d_in, const int* in_sizes, int n_in,
                              void* d_out, int out_size, void* d_ws, size_t ws_size,
                              hipStream_t stream) {
  const float* x   = (const float*)d_in[0];
  const float* ea  = (const float*)d_in[1];
  // only block index 3 (last scan iteration) matters
  const float* ew1 = (const float*)d_in[2]  + 3 * 384 * 128;
  const float* eb1 = (const float*)d_in[3]  + 3 * 128;
  const float* ew2 = (const float*)d_in[4]  + 3 * 128 * 128;
  const float* eb2 = (const float*)d_in[5]  + 3 * 128;
  const float* ew3 = (const float*)d_in[6]  + 3 * 128 * 128;
  const float* eb3 = (const float*)d_in[7]  + 3 * 128;
  const float* eg  = (const float*)d_in[8]  + 3 * 128;
  const float* ebt = (const float*)d_in[9]  + 3 * 128;
  const float* nw1 = (const float*)d_in[10] + 3 * 256 * 128;
  const float* nb1 = (const float*)d_in[11] + 3 * 128;
  const float* nw2 = (const float*)d_in[12] + 3 * 128 * 128;
  const float* nb2 = (const float*)d_in[13] + 3 * 128;
  const float* nw3 = (const float*)d_in[14] + 3 * 128 * 128;
  const float* nb3 = (const float*)d_in[15] + 3 * 128;
  const float* ng  = (const float*)d_in[16] + 3 * 128;
  const float* nbt = (const float*)d_in[17] + 3 * 128;
  const int* rowi  = (const int*)d_in[18];
  const int* coli  = rowi + NEDGE;

  // workspace: [agg 50000x128 f32 = 25,600,000 B][bf16 weight images 368,640 B]
  float* agg = (float*)d_ws;
  unsigned short* img = (unsigned short*)((char*)d_ws + 25600000);

  float* outx = (float*)d_out;
  float* oute = outx + (size_t)NNODE * D;

  hipMemsetAsync(agg, 0, (size_t)NNODE * D * sizeof(float), stream);
  prep_weights<<<576, 256, 0, stream>>>(ew1, ew2, ew3, nw1, nw2, nw3, img);
  mlp_fused<12, true><<<NEDGE / 128, 256, 0, stream>>>(
      x, ea, rowi, coli, img + 0, img + 61440, img + 81920,
      eb1, eb2, eb3, eg, ebt, oute, agg, NEDGE);
  mlp_fused<8, false><<<(NNODE + 127) / 128, 256, 0, stream>>>(
      x, agg, nullptr, nullptr, img + 102400, img + 143360, img + 163840,
      nb1, nb2, nb3, ng, nbt, outx, nullptr, NNODE);
}